// Round 1
// baseline (4645.778 us; speedup 1.0000x reference)
//
#include <hip/hip_runtime.h>
#include <cstddef>

// Problem constants (Attention_layer_56590489092432)
#define B_   16
#define S_   512
#define D_   1024
#define H_   16
#define DH_  64
#define BS_  8192          // B_*S_
#define EPS_ 1e-5f

// ---------------------------------------------------------------------------
// proj: out[b,h,s,e] = sum_d X[b*S+s, d] * W[h, d, e]
// grid (BS/64, H), block 256. 64x64 output tile, 4x4 per thread, K-step 16.
// ---------------------------------------------------------------------------
__global__ __launch_bounds__(256) void proj_kernel(
    const float* __restrict__ X, const float* __restrict__ W,
    float* __restrict__ out)
{
    __shared__ float As[16][65];
    __shared__ float Bs[16][65];
    const int tid = threadIdx.x;
    const int tx = tid & 15, ty = tid >> 4;
    const int m0 = blockIdx.x * 64;
    const int h  = blockIdx.y;
    const float* Wh = W + (size_t)h * D_ * DH_;

    float acc[4][4] = {};
    for (int k0 = 0; k0 < D_; k0 += 16) {
        {   // A tile 64(m) x 16(k), stored As[k][m]
            const int kk = tid & 15;
            const int mb = tid >> 4;
            #pragma unroll
            for (int r = 0; r < 4; ++r) {
                const int m = mb + r * 16;
                As[kk][m] = X[(size_t)(m0 + m) * D_ + k0 + kk];
            }
        }
        {   // B tile 16(k) x 64(e)
            const int n  = tid & 63;
            const int kb = tid >> 6;
            #pragma unroll
            for (int r = 0; r < 4; ++r) {
                const int k = kb + r * 4;
                Bs[k][n] = Wh[(size_t)(k0 + k) * DH_ + n];
            }
        }
        __syncthreads();
        #pragma unroll
        for (int kk = 0; kk < 16; ++kk) {
            float a[4], bb[4];
            #pragma unroll
            for (int i = 0; i < 4; ++i) a[i]  = As[kk][ty * 4 + i];
            #pragma unroll
            for (int j = 0; j < 4; ++j) bb[j] = Bs[kk][tx * 4 + j];
            #pragma unroll
            for (int i = 0; i < 4; ++i)
                #pragma unroll
                for (int j = 0; j < 4; ++j)
                    acc[i][j] += a[i] * bb[j];
        }
        __syncthreads();
    }
    #pragma unroll
    for (int i = 0; i < 4; ++i) {
        const int m = m0 + ty * 4 + i;
        const int b = m >> 9, s = m & 511;
        float* dst = out + ((size_t)(b * H_ + h) * S_ + s) * DH_ + tx * 4;
        #pragma unroll
        for (int j = 0; j < 4; ++j) dst[j] = acc[i][j];
    }
}

// ---------------------------------------------------------------------------
// mlp: C[m,n] = relu(sum_k A[m,k] * W[k,n] + bias[n])   (row-major, D_ x D_)
// grid (BS/64, D/64), block 256.
// ---------------------------------------------------------------------------
__global__ __launch_bounds__(256) void mlp_kernel(
    const float* __restrict__ A, const float* __restrict__ W,
    const float* __restrict__ bias, float* __restrict__ C)
{
    __shared__ float As[16][65];
    __shared__ float Bs[16][65];
    const int tid = threadIdx.x;
    const int tx = tid & 15, ty = tid >> 4;
    const int m0 = blockIdx.x * 64, n0 = blockIdx.y * 64;

    float acc[4][4] = {};
    for (int k0 = 0; k0 < D_; k0 += 16) {
        {
            const int kk = tid & 15;
            const int mb = tid >> 4;
            #pragma unroll
            for (int r = 0; r < 4; ++r) {
                const int m = mb + r * 16;
                As[kk][m] = A[(size_t)(m0 + m) * D_ + k0 + kk];
            }
        }
        {
            const int n  = tid & 63;
            const int kb = tid >> 6;
            #pragma unroll
            for (int r = 0; r < 4; ++r) {
                const int k = kb + r * 4;
                Bs[k][n] = W[(size_t)(k0 + k) * D_ + n0 + n];
            }
        }
        __syncthreads();
        #pragma unroll
        for (int kk = 0; kk < 16; ++kk) {
            float a[4], bb[4];
            #pragma unroll
            for (int i = 0; i < 4; ++i) a[i]  = As[kk][ty * 4 + i];
            #pragma unroll
            for (int j = 0; j < 4; ++j) bb[j] = Bs[kk][tx * 4 + j];
            #pragma unroll
            for (int i = 0; i < 4; ++i)
                #pragma unroll
                for (int j = 0; j < 4; ++j)
                    acc[i][j] += a[i] * bb[j];
        }
        __syncthreads();
    }
    #pragma unroll
    for (int i = 0; i < 4; ++i) {
        const int m = m0 + ty * 4 + i;
        #pragma unroll
        for (int j = 0; j < 4; ++j) {
            const int n = n0 + tx * 4 + j;
            const float v = acc[i][j] + bias[n];
            C[(size_t)m * D_ + n] = v > 0.f ? v : 0.f;
        }
    }
}

// ---------------------------------------------------------------------------
// scores: P[s,t] = 0.125 * sum_e Qn[z,s,e] * Kn[z,t,e];  z = b*H + h
// written to maps at [(h*B + b), s, t].  grid (8, 8, 256), block 256.
// ---------------------------------------------------------------------------
__global__ __launch_bounds__(256) void scores_kernel(
    const float* __restrict__ QN, const float* __restrict__ KN,
    float* __restrict__ mapsi)
{
    const int z = blockIdx.z;
    const int b = z >> 4, h = z & 15;
    const int s0 = blockIdx.x * 64, t0 = blockIdx.y * 64;
    const float* Q = QN + (size_t)z * S_ * DH_;
    const float* K = KN + (size_t)z * S_ * DH_;

    __shared__ float Qs[64][65];
    __shared__ float Ks[64][65];
    const int tid = threadIdx.x;
    const int e = tid & 63, r0 = tid >> 6;
    #pragma unroll
    for (int r = 0; r < 16; ++r) {
        const int row = r0 + r * 4;
        Qs[row][e] = Q[(size_t)(s0 + row) * DH_ + e];
        Ks[row][e] = K[(size_t)(t0 + row) * DH_ + e];
    }
    __syncthreads();

    const int tx = tid & 15, ty = tid >> 4;
    float acc[4][4] = {};
    for (int e2 = 0; e2 < 64; ++e2) {
        float a[4], bb[4];
        #pragma unroll
        for (int i = 0; i < 4; ++i) a[i]  = Qs[ty * 4 + i][e2];
        #pragma unroll
        for (int j = 0; j < 4; ++j) bb[j] = Ks[tx * 4 + j][e2];
        #pragma unroll
        for (int i = 0; i < 4; ++i)
            #pragma unroll
            for (int j = 0; j < 4; ++j)
                acc[i][j] += a[i] * bb[j];
    }
    float* P = mapsi + (size_t)(h * B_ + b) * S_ * S_;
    #pragma unroll
    for (int i = 0; i < 4; ++i) {
        const int s = s0 + ty * 4 + i;
        float* dst = P + (size_t)s * S_ + t0 + tx * 4;
        #pragma unroll
        for (int j = 0; j < 4; ++j) dst[j] = acc[i][j] * 0.125f;
    }
}

// ---------------------------------------------------------------------------
// o: O[b,s, h*64+e] = sum_t P[(h*B+b), s, t] * Vn[z, t, e];  z = b*H + h
// grid (8, 256), block 256. 64(s) x 64(e) tile, K-step 16 over t.
// ---------------------------------------------------------------------------
__global__ __launch_bounds__(256) void o_kernel(
    const float* __restrict__ mapsi, const float* __restrict__ VN,
    float* __restrict__ O)
{
    const int z = blockIdx.y;
    const int b = z >> 4, h = z & 15;
    const float* P = mapsi + (size_t)(h * B_ + b) * S_ * S_;
    const float* V = VN + (size_t)z * S_ * DH_;
    const int m0 = blockIdx.x * 64;

    __shared__ float As[16][65];
    __shared__ float Bs[16][65];
    const int tid = threadIdx.x;
    const int tx = tid & 15, ty = tid >> 4;

    float acc[4][4] = {};
    for (int k0 = 0; k0 < S_; k0 += 16) {
        {
            const int kk = tid & 15;
            const int mb = tid >> 4;
            #pragma unroll
            for (int r = 0; r < 4; ++r) {
                const int m = mb + r * 16;
                As[kk][m] = P[(size_t)(m0 + m) * S_ + k0 + kk];
            }
        }
        {
            const int n  = tid & 63;
            const int kb = tid >> 6;
            #pragma unroll
            for (int r = 0; r < 4; ++r) {
                const int k = kb + r * 4;
                Bs[k][n] = V[(size_t)(k0 + k) * DH_ + n];
            }
        }
        __syncthreads();
        #pragma unroll
        for (int kk = 0; kk < 16; ++kk) {
            float a[4], bb[4];
            #pragma unroll
            for (int i = 0; i < 4; ++i) a[i]  = As[kk][ty * 4 + i];
            #pragma unroll
            for (int j = 0; j < 4; ++j) bb[j] = Bs[kk][tx * 4 + j];
            #pragma unroll
            for (int i = 0; i < 4; ++i)
                #pragma unroll
                for (int j = 0; j < 4; ++j)
                    acc[i][j] += a[i] * bb[j];
        }
        __syncthreads();
    }
    #pragma unroll
    for (int i = 0; i < 4; ++i) {
        const int s = m0 + ty * 4 + i;
        float* dst = O + ((size_t)b * S_ + s) * D_ + h * DH_ + tx * 4;
        #pragma unroll
        for (int j = 0; j < 4; ++j) dst[j] = acc[i][j];
    }
}

// ---------------------------------------------------------------------------
// head LN (rows of 64, in place).  grid rows/4, block 256 (4 rows/block).
// ---------------------------------------------------------------------------
__global__ __launch_bounds__(256) void head_ln_kernel(
    float* __restrict__ buf, const float* __restrict__ g,
    const float* __restrict__ bb)
{
    const int tid = threadIdx.x;
    const int lane = tid & 63;
    const size_t row = (size_t)blockIdx.x * 4 + (tid >> 6);
    float x = buf[row * 64 + lane];
    float s = x;
    #pragma unroll
    for (int off = 32; off > 0; off >>= 1) s += __shfl_xor(s, off, 64);
    const float mean = s * (1.f / 64.f);
    const float d = x - mean;
    float q = d * d;
    #pragma unroll
    for (int off = 32; off > 0; off >>= 1) q += __shfl_xor(q, off, 64);
    const float rstd = rsqrtf(q * (1.f / 64.f) + EPS_);
    buf[row * 64 + lane] = d * rstd * g[lane] + bb[lane];
}

// ---------------------------------------------------------------------------
// ln over rows of 1024: out[m,:] = LN(A[m,:] + C[m,:]) * g + b
// grid BS, block 256 (4 elements/thread).
// ---------------------------------------------------------------------------
__global__ __launch_bounds__(256) void ln_add_kernel(
    const float* __restrict__ A, const float* __restrict__ C,
    const float* __restrict__ g, const float* __restrict__ bb,
    float* __restrict__ out)
{
    const int m = blockIdx.x;
    const float* a = A + (size_t)m * D_;
    const float* c = C + (size_t)m * D_;
    const int t = threadIdx.x;
    const int wave = t >> 6, lane = t & 63;
    __shared__ float red1[4];
    __shared__ float red2[4];

    float v[4];
    float s = 0.f;
    #pragma unroll
    for (int i = 0; i < 4; ++i) {
        const int idx = t + i * 256;
        v[i] = a[idx] + c[idx];
        s += v[i];
    }
    #pragma unroll
    for (int off = 32; off > 0; off >>= 1) s += __shfl_xor(s, off, 64);
    if (lane == 0) red1[wave] = s;
    __syncthreads();
    const float mean = (red1[0] + red1[1] + red1[2] + red1[3]) * (1.f / 1024.f);

    float q = 0.f;
    #pragma unroll
    for (int i = 0; i < 4; ++i) {
        const float d = v[i] - mean;
        q += d * d;
    }
    #pragma unroll
    for (int off = 32; off > 0; off >>= 1) q += __shfl_xor(q, off, 64);
    if (lane == 0) red2[wave] = q;
    __syncthreads();
    const float rstd =
        rsqrtf((red2[0] + red2[1] + red2[2] + red2[3]) * (1.f / 1024.f) + EPS_);

    float* o = out + (size_t)m * D_;
    #pragma unroll
    for (int i = 0; i < 4; ++i) {
        const int idx = t + i * 256;
        o[idx] = (v[i] - mean) * rstd * g[idx] + bb[idx];
    }
}

// ---------------------------------------------------------------------------
extern "C" void kernel_launch(void* const* d_in, const int* in_sizes, int n_in,
                              void* d_out, int out_size, void* d_ws, size_t ws_size,
                              hipStream_t stream)
{
    const float* inputs = (const float*)d_in[0];
    const float* Wq  = (const float*)d_in[1];
    const float* Wk  = (const float*)d_in[2];
    const float* Wv  = (const float*)d_in[3];
    const float* qg  = (const float*)d_in[4];
    const float* qb  = (const float*)d_in[5];
    const float* kg  = (const float*)d_in[6];
    const float* kb  = (const float*)d_in[7];
    const float* vg  = (const float*)d_in[8];
    const float* vb  = (const float*)d_in[9];
    const float* l0g = (const float*)d_in[10];
    const float* l0b = (const float*)d_in[11];
    const float* l1g = (const float*)d_in[12];
    const float* l1b = (const float*)d_in[13];
    const float* mW  = (const float*)d_in[14];
    const float* mB  = (const float*)d_in[15];

    float* xout = (float*)d_out;                       // (B,S,D)
    float* maps = xout + (size_t)BS_ * D_;             // (NB, H*B, S, S)

    const size_t BUF = (size_t)BS_ * D_;               // 8388608 floats
    float* ws = (float*)d_ws;
    float* QN  = ws;                                   // (B,H,S,dh)
    float* KN  = QN + BUF;
    float* VN  = KN + BUF;
    float* O   = VN + BUF;                             // (B,S,D) attn out / h1
    float* NEW = O + BUF;                              // (B,S,D)
    float* HT  = NEW + BUF;                            // (B,S,D) h0
    // total ws use: 6 * 33.55 MB = 201 MB

    const dim3 blk(256);
    for (int i = 0; i < 2; ++i) {
        const float* xin = (i == 0) ? inputs : xout;   // block0 x -> d_out x region
        const float* Wqi = Wq + (size_t)i * H_ * D_ * DH_;
        const float* Wki = Wk + (size_t)i * H_ * D_ * DH_;
        const float* Wvi = Wv + (size_t)i * H_ * D_ * DH_;
        float* mapsi = maps + (size_t)i * H_ * B_ * S_ * S_;

        proj_kernel<<<dim3(BS_ / 64, H_), blk, 0, stream>>>(xin, Wqi, QN);
        proj_kernel<<<dim3(BS_ / 64, H_), blk, 0, stream>>>(xin, Wki, KN);
        proj_kernel<<<dim3(BS_ / 64, H_), blk, 0, stream>>>(xin, Wvi, VN);

        head_ln_kernel<<<dim3(B_ * H_ * S_ / 4), blk, 0, stream>>>(QN, qg + i * DH_, qb + i * DH_);
        head_ln_kernel<<<dim3(B_ * H_ * S_ / 4), blk, 0, stream>>>(KN, kg + i * DH_, kb + i * DH_);
        head_ln_kernel<<<dim3(B_ * H_ * S_ / 4), blk, 0, stream>>>(VN, vg + i * DH_, vb + i * DH_);

        scores_kernel<<<dim3(8, 8, B_ * H_), blk, 0, stream>>>(QN, KN, mapsi);
        o_kernel<<<dim3(8, B_ * H_), blk, 0, stream>>>(mapsi, VN, O);

        ln_add_kernel<<<dim3(BS_), blk, 0, stream>>>(xin, O, l0g + i * D_, l0b + i * D_, NEW);

        const float* W0 = mW + ((size_t)i * 2 + 0) * D_ * D_;
        const float* W1 = mW + ((size_t)i * 2 + 1) * D_ * D_;
        const float* b0 = mB + ((size_t)i * 2 + 0) * D_;
        const float* b1 = mB + ((size_t)i * 2 + 1) * D_;
        mlp_kernel<<<dim3(BS_ / 64, D_ / 64), blk, 0, stream>>>(NEW, W0, b0, HT);
        mlp_kernel<<<dim3(BS_ / 64, D_ / 64), blk, 0, stream>>>(HT, W1, b1, O);

        ln_add_kernel<<<dim3(BS_), blk, 0, stream>>>(NEW, O, l1g + i * D_, l1b + i * D_, xout);
    }
}